// Round 5
// baseline (147.264 us; speedup 1.0000x reference)
//
#include <hip/hip_runtime.h>
#include <math.h>

#define DIM 128
#define NUM_NEG 20
#define BATCH 16384
#define INV_T (1.0f / 0.07f)
#define NROWS 21
#define NUM_NODES 100000

typedef _Float16 half8 __attribute__((ext_vector_type(8)));

// ---- fp32 -> fp16 table conversion (streams 51.2 MB -> 25.6 MB in d_ws) ----
__global__ __launch_bounds__(256) void convert_f16(
    const float* __restrict__ in, half8* __restrict__ out, int nchunk)
{
    for (int i = blockIdx.x * blockDim.x + threadIdx.x; i < nchunk;
         i += gridDim.x * blockDim.x) {
        const float4* p = reinterpret_cast<const float4*>(in) + (size_t)i * 2;
        const float4 a = p[0], b = p[1];
        half8 h;
        h[0] = (_Float16)a.x; h[1] = (_Float16)a.y;
        h[2] = (_Float16)a.z; h[3] = (_Float16)a.w;
        h[4] = (_Float16)b.x; h[5] = (_Float16)b.y;
        h[6] = (_Float16)b.z; h[7] = (_Float16)b.w;
        out[i] = h;
    }
}

// ---- fp16 gather kernel: one wave per batch element, 4 groups x 16 lanes.
// A 256 B fp16 row is covered by ONE 16-lane x 16B load (4 cache lines vs 8
// for fp32) -> halves the random-line count that bounds this kernel.
__global__ __launch_bounds__(256) void infonce_f16(
    const half8* __restrict__ tab,   // [NUM_NODES][16] chunks of 8 halves
    const int* __restrict__ targets,
    const int* __restrict__ contexts,
    const int* __restrict__ negatives,
    float* __restrict__ out)
{
    __shared__ float block_part[4];
    const int lane = threadIdx.x & 63;
    const int wib  = threadIdx.x >> 6;
    const int b    = blockIdx.x * 4 + wib;
    const int sub  = lane & 15;          // 8-half chunk within the row
    const int grp  = lane >> 4;          // row-group 0..3

    // phase 1: all index loads
    const int* __restrict__ negb = negatives + b * NUM_NEG;
    int node[6];
    #pragma unroll
    for (int it = 0; it < 6; ++it) {
        const int r = it * 4 + grp;      // 0..23 (21..23 invalid -> alias row 20)
        const int k = (r == 0) ? 0 : ((r <= NUM_NEG) ? (r - 1) : (NUM_NEG - 1));
        node[it] = (r == 0) ? contexts[b] : negb[k];
    }
    const int t_idx = targets[b];

    // phase 2: all row gathers back-to-back (max MLP)
    const half8 th = tab[(size_t)t_idx * 16 + sub];
    half8 vh[6];
    #pragma unroll
    for (int it = 0; it < 6; ++it)
        vh[it] = tab[(size_t)node[it] * 16 + sub];

    float tf[8];
    #pragma unroll
    for (int j = 0; j < 8; ++j) tf[j] = (float)th[j];

    // phase 3: dot + 16-lane reduce per slot
    float score[6];
    #pragma unroll
    for (int it = 0; it < 6; ++it) {
        float p = 0.0f;
        #pragma unroll
        for (int j = 0; j < 8; ++j) p = fmaf(tf[j], (float)vh[it][j], p);
        p += __shfl_xor(p, 1);
        p += __shfl_xor(p, 2);
        p += __shfl_xor(p, 4);
        p += __shfl_xor(p, 8);
        const int r = it * 4 + grp;
        score[it] = (r < NROWS) ? p * INV_T : -INFINITY;
    }

    // phase 4: logsumexp (local 6, then merge across 4 groups)
    float m = score[0];
    #pragma unroll
    for (int i = 1; i < 6; ++i) m = fmaxf(m, score[i]);
    float s = 0.0f;
    #pragma unroll
    for (int i = 0; i < 6; ++i) s += expf(score[i] - m);

    #pragma unroll
    for (int mask = 16; mask <= 32; mask <<= 1) {
        const float mo = __shfl_xor(m, mask);
        const float so = __shfl_xor(s, mask);
        const float mn = fmaxf(m, mo);
        s = s * expf(m - mn) + so * expf(mo - mn);
        m = mn;
    }

    const float pos = __shfl(score[0], 0);
    const float loss = (m + logf(s) - pos) * (1.0f / BATCH);

    if (lane == 0) block_part[wib] = loss;
    __syncthreads();
    if (threadIdx.x == 0) {
        atomicAdd(out, block_part[0] + block_part[1] +
                       block_part[2] + block_part[3]);
    }
}

// ---- fp32 fallback (R3 kernel) if d_ws is too small for the fp16 table ----
__global__ __launch_bounds__(256) void infonce_f32(
    const float* __restrict__ emb,
    const int* __restrict__ targets,
    const int* __restrict__ contexts,
    const int* __restrict__ negatives,
    float* __restrict__ out)
{
    __shared__ float block_part[4];
    const int lane = threadIdx.x & 63;
    const int wib  = threadIdx.x >> 6;
    const int b    = blockIdx.x * 4 + wib;
    const int sub  = lane & 15;
    const int grp  = lane >> 4;

    const int* __restrict__ negb = negatives + b * NUM_NEG;
    int node[6];
    #pragma unroll
    for (int it = 0; it < 6; ++it) {
        const int r = it * 4 + grp;
        const int k = (r == 0) ? 0 : ((r <= NUM_NEG) ? (r - 1) : (NUM_NEG - 1));
        node[it] = (r == 0) ? contexts[b] : negb[k];
    }
    const int t_idx = targets[b];

    const float4* tp =
        reinterpret_cast<const float4*>(emb + (size_t)t_idx * DIM + sub * 8);
    const float4 t0 = tp[0];
    const float4 t1 = tp[1];

    float4 r0[6], r1[6];
    #pragma unroll
    for (int it = 0; it < 6; ++it) {
        const float4* vp = reinterpret_cast<const float4*>(
            emb + (size_t)node[it] * DIM + sub * 8);
        r0[it] = vp[0];
        r1[it] = vp[1];
    }

    float score[6];
    #pragma unroll
    for (int it = 0; it < 6; ++it) {
        float p = t0.x * r0[it].x + t0.y * r0[it].y
                + t0.z * r0[it].z + t0.w * r0[it].w
                + t1.x * r1[it].x + t1.y * r1[it].y
                + t1.z * r1[it].z + t1.w * r1[it].w;
        p += __shfl_xor(p, 1);
        p += __shfl_xor(p, 2);
        p += __shfl_xor(p, 4);
        p += __shfl_xor(p, 8);
        const int r = it * 4 + grp;
        score[it] = (r < NROWS) ? p * INV_T : -INFINITY;
    }

    float m = score[0];
    #pragma unroll
    for (int i = 1; i < 6; ++i) m = fmaxf(m, score[i]);
    float s = 0.0f;
    #pragma unroll
    for (int i = 0; i < 6; ++i) s += expf(score[i] - m);

    #pragma unroll
    for (int mask = 16; mask <= 32; mask <<= 1) {
        const float mo = __shfl_xor(m, mask);
        const float so = __shfl_xor(s, mask);
        const float mn = fmaxf(m, mo);
        s = s * expf(m - mn) + so * expf(mo - mn);
        m = mn;
    }

    const float pos = __shfl(score[0], 0);
    const float loss = (m + logf(s) - pos) * (1.0f / BATCH);

    if (lane == 0) block_part[wib] = loss;
    __syncthreads();
    if (threadIdx.x == 0) {
        atomicAdd(out, block_part[0] + block_part[1] +
                       block_part[2] + block_part[3]);
    }
}

extern "C" void kernel_launch(void* const* d_in, const int* in_sizes, int n_in,
                              void* d_out, int out_size, void* d_ws, size_t ws_size,
                              hipStream_t stream) {
    const float* emb       = (const float*)d_in[0];
    const int*   targets   = (const int*)d_in[1];
    const int*   contexts  = (const int*)d_in[2];
    const int*   negatives = (const int*)d_in[3];
    float* out = (float*)d_out;

    hipMemsetAsync(out, 0, sizeof(float), stream);

    const size_t need = (size_t)NUM_NODES * DIM * sizeof(_Float16);  // 25.6 MB
    if (ws_size >= need) {
        half8* tab = (half8*)d_ws;
        const int nchunk = NUM_NODES * DIM / 8;  // 1.6M
        convert_f16<<<dim3(2048), dim3(256), 0, stream>>>(emb, tab, nchunk);
        infonce_f16<<<dim3(BATCH / 4), dim3(256), 0, stream>>>(
            tab, targets, contexts, negatives, out);
    } else {
        infonce_f32<<<dim3(BATCH / 4), dim3(256), 0, stream>>>(
            emb, targets, contexts, negatives, out);
    }
}

// Round 6
// 105.304 us; speedup vs baseline: 1.3985x; 1.3985x over previous
//
#include <hip/hip_runtime.h>
#include <math.h>

#define DIM 128
#define NUM_NEG 20
#define BATCH 16384
#define INV_T (1.0f / 0.07f)
#define NROWS 21
#define NUM_NODES 100000
#define NBLOCK (BATCH / 4)   // 4096 blocks, 4 waves each

typedef _Float16 half8 __attribute__((ext_vector_type(8)));

// ---- fp32 -> fp16 table conversion (streams 51.2 MB -> 25.6 MB in d_ws) ----
__global__ __launch_bounds__(256) void convert_f16(
    const float* __restrict__ in, half8* __restrict__ out, int nchunk)
{
    for (int i = blockIdx.x * blockDim.x + threadIdx.x; i < nchunk;
         i += gridDim.x * blockDim.x) {
        const float4* p = reinterpret_cast<const float4*>(in) + (size_t)i * 2;
        const float4 a = p[0], b = p[1];
        half8 h;
        h[0] = (_Float16)a.x; h[1] = (_Float16)a.y;
        h[2] = (_Float16)a.z; h[3] = (_Float16)a.w;
        h[4] = (_Float16)b.x; h[5] = (_Float16)b.y;
        h[6] = (_Float16)b.z; h[7] = (_Float16)b.w;
        out[i] = h;
    }
}

// ---- fp16 gather kernel: identical to R5 except the block result goes to a
// unique d_ws slot instead of a same-address atomicAdd (the suspected 34
// cyc/atomic serial bottleneck). ----
__global__ __launch_bounds__(256) void infonce_f16(
    const half8* __restrict__ tab,   // [NUM_NODES][16] chunks of 8 halves
    const int* __restrict__ targets,
    const int* __restrict__ contexts,
    const int* __restrict__ negatives,
    float* __restrict__ part)        // [NBLOCK] partials
{
    __shared__ float block_part[4];
    const int lane = threadIdx.x & 63;
    const int wib  = threadIdx.x >> 6;
    const int b    = blockIdx.x * 4 + wib;
    const int sub  = lane & 15;          // 8-half chunk within the row
    const int grp  = lane >> 4;          // row-group 0..3

    // phase 1: all index loads
    const int* __restrict__ negb = negatives + b * NUM_NEG;
    int node[6];
    #pragma unroll
    for (int it = 0; it < 6; ++it) {
        const int r = it * 4 + grp;      // 0..23 (21..23 invalid -> alias row 20)
        const int k = (r == 0) ? 0 : ((r <= NUM_NEG) ? (r - 1) : (NUM_NEG - 1));
        node[it] = (r == 0) ? contexts[b] : negb[k];
    }
    const int t_idx = targets[b];

    // phase 2: all row gathers back-to-back (max MLP)
    const half8 th = tab[(size_t)t_idx * 16 + sub];
    half8 vh[6];
    #pragma unroll
    for (int it = 0; it < 6; ++it)
        vh[it] = tab[(size_t)node[it] * 16 + sub];

    float tf[8];
    #pragma unroll
    for (int j = 0; j < 8; ++j) tf[j] = (float)th[j];

    // phase 3: dot + 16-lane reduce per slot
    float score[6];
    #pragma unroll
    for (int it = 0; it < 6; ++it) {
        float p = 0.0f;
        #pragma unroll
        for (int j = 0; j < 8; ++j) p = fmaf(tf[j], (float)vh[it][j], p);
        p += __shfl_xor(p, 1);
        p += __shfl_xor(p, 2);
        p += __shfl_xor(p, 4);
        p += __shfl_xor(p, 8);
        const int r = it * 4 + grp;
        score[it] = (r < NROWS) ? p * INV_T : -INFINITY;
    }

    // phase 4: logsumexp (local 6, then merge across 4 groups)
    float m = score[0];
    #pragma unroll
    for (int i = 1; i < 6; ++i) m = fmaxf(m, score[i]);
    float s = 0.0f;
    #pragma unroll
    for (int i = 0; i < 6; ++i) s += expf(score[i] - m);

    #pragma unroll
    for (int mask = 16; mask <= 32; mask <<= 1) {
        const float mo = __shfl_xor(m, mask);
        const float so = __shfl_xor(s, mask);
        const float mn = fmaxf(m, mo);
        s = s * expf(m - mn) + so * expf(mo - mn);
        m = mn;
    }

    const float pos = __shfl(score[0], 0);
    const float loss = (m + logf(s) - pos) * (1.0f / BATCH);

    if (lane == 0) block_part[wib] = loss;
    __syncthreads();
    if (threadIdx.x == 0) {
        part[blockIdx.x] = block_part[0] + block_part[1] +
                           block_part[2] + block_part[3];
    }
}

// ---- final reduction: 4096 partials -> out[0], one block, no atomics ----
__global__ __launch_bounds__(1024) void reduce_partials(
    const float4* __restrict__ part4, float* __restrict__ out)
{
    __shared__ float ws[16];
    const float4 v = part4[threadIdx.x];         // 1024 x float4 = 4096 floats
    float s = v.x + v.y + v.z + v.w;
    #pragma unroll
    for (int off = 32; off; off >>= 1) s += __shfl_xor(s, off);
    const int wave = threadIdx.x >> 6;
    if ((threadIdx.x & 63) == 0) ws[wave] = s;
    __syncthreads();
    if (threadIdx.x == 0) {
        float t = 0.0f;
        #pragma unroll
        for (int i = 0; i < 16; ++i) t += ws[i];
        out[0] = t;
    }
}

// ---- fp32 fallback with the old atomic ending (only if d_ws is tiny) ----
__global__ __launch_bounds__(256) void infonce_f32_atomic(
    const float* __restrict__ emb,
    const int* __restrict__ targets,
    const int* __restrict__ contexts,
    const int* __restrict__ negatives,
    float* __restrict__ out)
{
    __shared__ float block_part[4];
    const int lane = threadIdx.x & 63;
    const int wib  = threadIdx.x >> 6;
    const int b    = blockIdx.x * 4 + wib;
    const int sub  = lane & 15;
    const int grp  = lane >> 4;

    const int* __restrict__ negb = negatives + b * NUM_NEG;
    int node[6];
    #pragma unroll
    for (int it = 0; it < 6; ++it) {
        const int r = it * 4 + grp;
        const int k = (r == 0) ? 0 : ((r <= NUM_NEG) ? (r - 1) : (NUM_NEG - 1));
        node[it] = (r == 0) ? contexts[b] : negb[k];
    }
    const int t_idx = targets[b];

    const float4* tp =
        reinterpret_cast<const float4*>(emb + (size_t)t_idx * DIM + sub * 8);
    const float4 t0 = tp[0];
    const float4 t1 = tp[1];

    float score[6];
    #pragma unroll
    for (int it = 0; it < 6; ++it) {
        const float4* vp = reinterpret_cast<const float4*>(
            emb + (size_t)node[it] * DIM + sub * 8);
        const float4 v0 = vp[0];
        const float4 v1 = vp[1];
        float p = t0.x * v0.x + t0.y * v0.y + t0.z * v0.z + t0.w * v0.w
                + t1.x * v1.x + t1.y * v1.y + t1.z * v1.z + t1.w * v1.w;
        p += __shfl_xor(p, 1);
        p += __shfl_xor(p, 2);
        p += __shfl_xor(p, 4);
        p += __shfl_xor(p, 8);
        const int r = it * 4 + grp;
        score[it] = (r < NROWS) ? p * INV_T : -INFINITY;
    }

    float m = score[0];
    #pragma unroll
    for (int i = 1; i < 6; ++i) m = fmaxf(m, score[i]);
    float s = 0.0f;
    #pragma unroll
    for (int i = 0; i < 6; ++i) s += expf(score[i] - m);

    #pragma unroll
    for (int mask = 16; mask <= 32; mask <<= 1) {
        const float mo = __shfl_xor(m, mask);
        const float so = __shfl_xor(s, mask);
        const float mn = fmaxf(m, mo);
        s = s * expf(m - mn) + so * expf(mo - mn);
        m = mn;
    }

    const float pos = __shfl(score[0], 0);
    const float loss = (m + logf(s) - pos) * (1.0f / BATCH);

    if (lane == 0) block_part[wib] = loss;
    __syncthreads();
    if (threadIdx.x == 0) {
        atomicAdd(out, block_part[0] + block_part[1] +
                       block_part[2] + block_part[3]);
    }
}

extern "C" void kernel_launch(void* const* d_in, const int* in_sizes, int n_in,
                              void* d_out, int out_size, void* d_ws, size_t ws_size,
                              hipStream_t stream) {
    const float* emb       = (const float*)d_in[0];
    const int*   targets   = (const int*)d_in[1];
    const int*   contexts  = (const int*)d_in[2];
    const int*   negatives = (const int*)d_in[3];
    float* out = (float*)d_out;

    const size_t tab_bytes  = (size_t)NUM_NODES * DIM * sizeof(_Float16); // 25.6 MB
    const size_t part_bytes = (size_t)NBLOCK * sizeof(float);             // 16 KB

    if (ws_size >= tab_bytes + part_bytes) {
        half8* tab  = (half8*)d_ws;
        float* part = (float*)((char*)d_ws + tab_bytes);  // 16B-aligned
        const int nchunk = NUM_NODES * DIM / 8;  // 1.6M
        convert_f16<<<dim3(2048), dim3(256), 0, stream>>>(emb, tab, nchunk);
        infonce_f16<<<dim3(NBLOCK), dim3(256), 0, stream>>>(
            tab, targets, contexts, negatives, part);
        reduce_partials<<<dim3(1), dim3(1024), 0, stream>>>(
            (const float4*)part, out);
    } else {
        hipMemsetAsync(out, 0, sizeof(float), stream);
        infonce_f32_atomic<<<dim3(NBLOCK), dim3(256), 0, stream>>>(
            emb, targets, contexts, negatives, out);
    }
}